// Round 1
// 85.854 us; speedup vs baseline: 1.0222x; 1.0222x over previous
//
#include <hip/hip_runtime.h>
#include <math.h>

// JacobiMachine: 1000 steps of masked 5-point Jacobi averaging on 512x512.
// Spectral method (exact): step 1 explicit, steps 2..1000 via eigen-basis
//   phi_m[i]=sin(m*pi*i/511), lam_mn=0.5*(cos(m*pi/511)+cos(n*pi/511)),
// keeping the two surviving corners m in {1..64} u {447..510} (128 modes/dim,
// largest discarded |lam|^999 ~ 3e-18).
//
// Round 8: (a) 4 output rows/block in m1/m4 -> halve their L2 traffic
// (64MB -> 32MB each); (b) fuse m2+m3 into k_m23 (E row p depends only on
// D row p, so one block per p computes D's row in LDS then E's row) --
// removes one graph node, the D buffer round-trip, m2's atomics and the
// D zero-fill. Harness floor ~70us (256MB re-poison fills at ~40us visible
// in rocprof); controllable share is the ~18us of kernels+nodes.

#define HW 512
#define NP 128

__device__ __forceinline__ int mode_of(int p) {   // p=0..127 -> {1..64} u {447..510}
    return (p < 64) ? (p + 1) : (p + 383);
}

__device__ __forceinline__ float gauss(const float* __restrict__ X,
                                       const float* __restrict__ Y, int idx) {
    float dx = X[idx] - 0.5f, dy = Y[idx] - 0.5f;
    return expf(-50.0f * (dx * dx + dy * dy));
}

// Block ranges:
//  [0,1024)    x1[idx] = masked 5-pt avg of gaussian (== one reference step)
//  [1024,1280) S[p][i]  = sin(m_p*i*pi/511)      (p-major, for m1/m23/m4)
//  [1280,1536) ST[i][p] = sin(m_p*i*pi/511)      (i-major, coalesced in m23 ph1)
//  [1536,1600) L[p][q]  = lam_pq^999*(2/511)^2   (fp64 pow, sign kept, once)
//  [1600,1664) C1 = 0   (atomic target for k_m1)
__global__ void k_prep(const float* __restrict__ X, const float* __restrict__ Y,
                       float* __restrict__ x1, float* __restrict__ S,
                       float* __restrict__ ST, float* __restrict__ L,
                       float* __restrict__ C1) {
    int b = blockIdx.x, t = threadIdx.x;
    if (b < 1024) {
        int idx = b * 256 + t;
        int i = idx >> 9, j = idx & 511;
        float v = 0.0f;
        if (i > 0 && i < HW - 1 && j > 0 && j < HW - 1) {
            v = 0.25f * (gauss(X, Y, idx - HW) + gauss(X, Y, idx + HW) +
                         gauss(X, Y, idx - 1)  + gauss(X, Y, idx + 1));
        }
        x1[idx] = v;
    } else if (b < 1280) {
        int idx = (b - 1024) * 256 + t;
        int p = idx >> 9, i = idx & 511;
        long tt = ((long)mode_of(p) * (long)i) % 1022;   // exact reduction
        S[idx] = (float)sin((double)tt * (M_PI / 511.0));
    } else if (b < 1536) {
        int idx = (b - 1280) * 256 + t;
        int i = idx >> 7, p = idx & 127;
        long tt = ((long)mode_of(p) * (long)i) % 1022;
        ST[idx] = (float)sin((double)tt * (M_PI / 511.0));
    } else if (b < 1600) {
        int idx = (b - 1536) * 256 + t;                  // 16384 total
        int p = idx >> 7, q = idx & 127;
        double lp = cos((double)mode_of(p) * M_PI / 511.0);
        double lq = cos((double)mode_of(q) * M_PI / 511.0);
        double lam = 0.5 * (lp + lq);
        double mag = pow(fabs(lam), 999.0);
        if (lam < 0.0) mag = -mag;                       // 999 odd
        L[idx] = (float)(mag * (2.0 / 511.0) * (2.0 / 511.0));
    } else {
        ((float4*)C1)[(b - 1600) * 256 + t] = float4{0.f, 0.f, 0.f, 0.f};
    }
}

// C1[p][j] += sum_{i in chunk} S[p,i]*x1[i,j]
// grid (jc=2, pg=32, ic=8) x 256 = 512 blocks (8 waves/CU), 4 p-rows/block:
// halves x1 L2 re-reads vs R7 (64MB -> 32MB) with 4-chain ILP.
__global__ void k_m1(const float* __restrict__ S, const float* __restrict__ x1,
                     float* __restrict__ C1) {
    int j = blockIdx.x * 256 + threadIdx.x;
    int p0 = blockIdx.y * 4;
    int i0 = blockIdx.z * 64;
    const float* S0 = S + p0 * HW + i0;        // wave-uniform -> scalar loads
    const float* S1 = S0 + HW;
    const float* S2 = S1 + HW;
    const float* S3 = S2 + HW;
    const float* xp = x1 + i0 * HW + j;        // coalesced, L2-resident
    float a0 = 0.f, a1 = 0.f, a2 = 0.f, a3 = 0.f;
    #pragma unroll 8
    for (int i = 0; i < 64; i++) {
        float x = xp[i * HW];
        a0 += S0[i] * x;
        a1 += S1[i] * x;
        a2 += S2[i] * x;
        a3 += S3[i] * x;
    }
    unsafeAtomicAdd(&C1[(p0 + 0) * HW + j], a0);
    unsafeAtomicAdd(&C1[(p0 + 1) * HW + j], a1);
    unsafeAtomicAdd(&C1[(p0 + 2) * HW + j], a2);
    unsafeAtomicAdd(&C1[(p0 + 3) * HW + j], a3);
}

// Fused m2+m3: one block per p (128 blocks x 128 threads).
// Phase 1: drow[q] = L[p,q] * sum_{j=0..511} C1[p,j]*ST[j,q]  (D row, LDS only)
// Phase 2: E[p][j] = sum_q drow[q]*S[q,j]                     (S coalesced)
// E row p depends only on D row p, so no global D, no atomics, no extra node.
__global__ void k_m23(const float* __restrict__ C1, const float* __restrict__ ST,
                      const float* __restrict__ L, const float* __restrict__ S,
                      float* __restrict__ E) {
    __shared__ float c1[HW];
    __shared__ float drow[NP];
    int p = blockIdx.x, t = threadIdx.x;       // t = q in phase 1
    #pragma unroll
    for (int k = 0; k < 4; k++) c1[t + k * NP] = C1[p * HW + t + k * NP];
    __syncthreads();
    // Phase 1: 4 independent chains over j (stride-1 coalesced ST reads).
    float b0 = 0.f, b1 = 0.f, b2 = 0.f, b3 = 0.f;
    #pragma unroll 8
    for (int j = 0; j < HW; j += 4) {
        b0 += c1[j + 0] * ST[(j + 0) * NP + t];
        b1 += c1[j + 1] * ST[(j + 1) * NP + t];
        b2 += c1[j + 2] * ST[(j + 2) * NP + t];
        b3 += c1[j + 3] * ST[(j + 3) * NP + t];
    }
    drow[t] = ((b0 + b1) + (b2 + b3)) * L[p * NP + t];
    __syncthreads();
    // Phase 2: thread t produces E[p][t + k*128], k=0..3 (coalesced S reads).
    float e0 = 0.f, e1 = 0.f, e2 = 0.f, e3 = 0.f;
    #pragma unroll 8
    for (int q = 0; q < NP; q++) {
        float d = drow[q];
        const float* Sq = S + q * HW + t;
        e0 += d * Sq[0];
        e1 += d * Sq[128];
        e2 += d * Sq[256];
        e3 += d * Sq[384];
    }
    E[p * HW + t + 0]   = e0;
    E[p * HW + t + 128] = e1;
    E[p * HW + t + 256] = e2;
    E[p * HW + t + 384] = e3;
}

// out[i][j] = sum_p S[p,i]*E[p,j]
// grid (jc=2, ig=128) x 256 = 256 blocks, 4 i-rows/block: halves E L2 re-reads
// vs R7 (64MB -> 32MB). unroll 16 + 4 chains keeps >=16 loads in flight to
// cover L2 latency at 4 waves/CU. Boundary exact 0 via S[p][0]=S[p][511]=0.
__global__ void k_m4(const float* __restrict__ S, const float* __restrict__ E,
                     float* __restrict__ out) {
    int j = blockIdx.x * 256 + threadIdx.x;
    int i0 = blockIdx.y * 4;
    float a0 = 0.f, a1 = 0.f, a2 = 0.f, a3 = 0.f;
    #pragma unroll 16
    for (int p = 0; p < NP; p++) {
        float e = E[p * HW + j];               // coalesced
        a0 += S[p * HW + i0 + 0] * e;          // wave-uniform -> scalar
        a1 += S[p * HW + i0 + 1] * e;
        a2 += S[p * HW + i0 + 2] * e;
        a3 += S[p * HW + i0 + 3] * e;
    }
    out[(i0 + 0) * HW + j] = a0;
    out[(i0 + 1) * HW + j] = a1;
    out[(i0 + 2) * HW + j] = a2;
    out[(i0 + 3) * HW + j] = a3;
}

// ---------------- launcher ----------------

extern "C" void kernel_launch(void* const* d_in, const int* in_sizes, int n_in,
                              void* d_out, int out_size, void* d_ws, size_t ws_size,
                              hipStream_t stream) {
    const float* X = (const float*)d_in[0];
    const float* Y = (const float*)d_in[1];
    float* out = (float*)d_out;

    float* ws = (float*)d_ws;
    float* x1 = ws;                       // 512*512
    float* S  = x1 + HW * HW;             // 128*512
    float* ST = S + NP * HW;              // 512*128
    float* L  = ST + HW * NP;             // 128*128
    float* C1 = L + NP * NP;              // 128*512
    float* E  = C1 + NP * HW;             // 128*512

    k_prep<<<dim3(1664),        dim3(256), 0, stream>>>(X, Y, x1, S, ST, L, C1);
    k_m1  <<<dim3(2, 32, 8),    dim3(256), 0, stream>>>(S, x1, C1);
    k_m23 <<<dim3(NP),          dim3(128), 0, stream>>>(C1, ST, L, S, E);
    k_m4  <<<dim3(2, 128),      dim3(256), 0, stream>>>(S, E, out);
}

// Round 2
// 80.626 us; speedup vs baseline: 1.0884x; 1.0648x over previous
//
#include <hip/hip_runtime.h>
#include <math.h>

// JacobiMachine: 1000 steps of masked 5-point Jacobi averaging on 512x512.
// Spectral method (exact): step 1 explicit, steps 2..1000 via eigen-basis
//   phi_m[i]=sin(m*pi*i/511), lam_mn=0.5*(cos(m*pi/511)+cos(n*pi/511)),
// keeping the two surviving corners m in {1..64} u {447..510} (128 modes/dim,
// largest discarded |lam|^999 ~ 3e-18).
//
// Round 9:
//  (a) k_m23 -> 512 threads/block: 4-way j-split in phase 1 (LDS combine),
//      1 j/thread in phase 2. Per-thread L2 load chain 1024 -> 256, waves/block
//      2 -> 8 (was the latency-bound long pole).
//  (b) k_prep: pow(|lam|,999) -> binary exponentiation (17 fp64 muls);
//      fp64 sin count halved via S[511-m][i] = (-1)^(i+1) S[m][i] mirror.
//  (c) k_m1: 8 p-rows/block (x1 L2 traffic 32MB -> 16MB); partials to P[8]
//      with plain stores (no atomics, no C1 zero-fill in prep); k_m23 sums
//      the 8 partial rows on load.
// Harness floor ~70us (256MB re-poison fills at ~41us each in rocprof);
// controllable share is kernels + node gaps.

#define HW 512
#define NP 128

__device__ __forceinline__ int mode_of(int p) {   // p=0..127 -> {1..64} u {447..510}
    return (p < 64) ? (p + 1) : (p + 383);
}

__device__ __forceinline__ float gauss(const float* __restrict__ X,
                                       const float* __restrict__ Y, int idx) {
    float dx = X[idx] - 0.5f, dy = Y[idx] - 0.5f;
    return expf(-50.0f * (dx * dx + dy * dy));
}

// Block ranges:
//  [0,1024)    x1[idx] = masked 5-pt avg of gaussian (== one reference step)
//  [1024,1152) S[p][i], p<64 via fp64 sin; p>=64 mirrored: S[127-p][i]=(-1)^(i+1)S[p][i]
//  [1152,1280) ST[i][p] same values, i-major (coalesced in m23 phase 1)
//  [1280,1344) L[p][q] = lam_pq^999*(2/511)^2  (binary exponentiation, sign kept)
__global__ void k_prep(const float* __restrict__ X, const float* __restrict__ Y,
                       float* __restrict__ x1, float* __restrict__ S,
                       float* __restrict__ ST, float* __restrict__ L) {
    int b = blockIdx.x, t = threadIdx.x;
    if (b < 1024) {
        int idx = b * 256 + t;
        int i = idx >> 9, j = idx & 511;
        float v = 0.0f;
        if (i > 0 && i < HW - 1 && j > 0 && j < HW - 1) {
            v = 0.25f * (gauss(X, Y, idx - HW) + gauss(X, Y, idx + HW) +
                         gauss(X, Y, idx - 1)  + gauss(X, Y, idx + 1));
        }
        x1[idx] = v;
    } else if (b < 1152) {
        int idx = (b - 1024) * 256 + t;              // 64 rows x 512
        int pa = idx >> 9, i = idx & 511;            // pa in [0,64), m = pa+1
        long tt = ((long)(pa + 1) * (long)i) % 1022; // exact reduction
        float s = (float)sin((double)tt * (M_PI / 511.0));
        S[pa * HW + i] = s;
        S[(127 - pa) * HW + i] = (i & 1) ? s : -s;   // m' = 511-m mirror
    } else if (b < 1280) {
        int idx = (b - 1152) * 256 + t;              // 512 i x 64 pa
        int i = idx >> 6, pa = idx & 63;
        long tt = ((long)(pa + 1) * (long)i) % 1022;
        float s = (float)sin((double)tt * (M_PI / 511.0));
        ST[i * NP + pa] = s;
        ST[i * NP + (127 - pa)] = (i & 1) ? s : -s;
    } else {
        int idx = (b - 1280) * 256 + t;              // 16384 total
        int p = idx >> 7, q = idx & 127;
        double lp = cos((double)mode_of(p) * M_PI / 511.0);
        double lq = cos((double)mode_of(q) * M_PI / 511.0);
        double lam = 0.5 * (lp + lq);
        // |lam|^999 via square-and-multiply (999 = 0b1111100111)
        double r = 1.0, base = fabs(lam);
        int e = 999;
        #pragma unroll
        for (int k = 0; k < 10; k++) {
            if (e & 1) r *= base;
            base *= base;
            e >>= 1;
        }
        if (lam < 0.0) r = -r;                       // 999 odd
        L[idx] = (float)(r * (2.0 / 511.0) * (2.0 / 511.0));
    }
}

// P[iz][p][j] = sum_{i in chunk iz} S[p,i]*x1[i,j]   (plain stores, no atomics)
// grid (jc=2, pg=16, ic=8) x 256 = 256 blocks, 8 p-rows/block:
// x1 L2 traffic 16MB, 8-chain ILP, wave-uniform S rows -> scalar loads.
__global__ void k_m1(const float* __restrict__ S, const float* __restrict__ x1,
                     float* __restrict__ P) {
    int j = blockIdx.x * 256 + threadIdx.x;
    int p0 = blockIdx.y * 8;
    int iz = blockIdx.z;
    int i0 = iz * 64;
    const float* Sb = S + p0 * HW + i0;        // wave-uniform -> scalar loads
    const float* xp = x1 + i0 * HW + j;        // coalesced, L2-resident
    float a[8] = {0.f, 0.f, 0.f, 0.f, 0.f, 0.f, 0.f, 0.f};
    #pragma unroll 8
    for (int i = 0; i < 64; i++) {
        float x = xp[i * HW];
        #pragma unroll
        for (int k = 0; k < 8; k++) a[k] += Sb[k * HW + i] * x;
    }
    float* Pp = P + iz * NP * HW + p0 * HW + j;
    #pragma unroll
    for (int k = 0; k < 8; k++) Pp[k * HW] = a[k];
}

// Fused m2+m3, one block per p (128 blocks x 512 threads = 8 waves):
//  load:    c1[j]   = sum_{iz=0..7} P[iz][p][j]          (8 coalesced loads)
//  phase 1: part[t] = sum_{j in quarter jg} c1[j]*ST[j,q]  (t = jg*128+q)
//           drow[q] = (sum of 4 parts) * L[p,q]
//  phase 2: E[p][t] = sum_q drow[q]*S[q,t]               (1 j-column/thread)
// Per-thread L2 chain: 8 + 128 + 128 loads (was 1024 at 2 waves/block).
__global__ void k_m23(const float* __restrict__ P, const float* __restrict__ ST,
                      const float* __restrict__ L, const float* __restrict__ S,
                      float* __restrict__ E) {
    __shared__ float c1[HW];
    __shared__ float part[512];
    __shared__ float drow[NP];
    int p = blockIdx.x, t = threadIdx.x;
    // sum the 8 m1 partials for row p
    {
        const float* Pp = P + p * HW + t;
        float s0 = 0.f, s1 = 0.f;
        #pragma unroll
        for (int iz = 0; iz < 8; iz += 2) {
            s0 += Pp[iz * NP * HW];
            s1 += Pp[(iz + 1) * NP * HW];
        }
        c1[t] = s0 + s1;
    }
    __syncthreads();
    // phase 1: quarter-j reduction per thread group
    int q = t & 127, jg = t >> 7;
    const float* STp = ST + (jg * 128) * NP + q;
    const float* cc = c1 + jg * 128;
    float b0 = 0.f, b1 = 0.f;
    #pragma unroll 8
    for (int j = 0; j < 128; j += 2) {
        b0 += cc[j] * STp[j * NP];
        b1 += cc[j + 1] * STp[(j + 1) * NP];
    }
    part[t] = b0 + b1;
    __syncthreads();
    if (t < NP)
        drow[t] = (part[t] + part[t + 128] + part[t + 256] + part[t + 384]) * L[p * NP + t];
    __syncthreads();
    // phase 2: one output column per thread (S reads coalesced, drow broadcast)
    float e0 = 0.f, e1 = 0.f;
    #pragma unroll 8
    for (int qq = 0; qq < NP; qq += 2) {
        e0 += drow[qq] * S[qq * HW + t];
        e1 += drow[qq + 1] * S[(qq + 1) * HW + t];
    }
    E[p * HW + t] = e0 + e1;
}

// out[i][j] = sum_p S[p,i]*E[p,j]
// grid (jc=2, ig=128) x 256 = 256 blocks, 4 i-rows/block (32MB E L2 traffic).
// Boundary exact 0 via S[p][0]=S[p][511]=0.
__global__ void k_m4(const float* __restrict__ S, const float* __restrict__ E,
                     float* __restrict__ out) {
    int j = blockIdx.x * 256 + threadIdx.x;
    int i0 = blockIdx.y * 4;
    float a0 = 0.f, a1 = 0.f, a2 = 0.f, a3 = 0.f;
    #pragma unroll 16
    for (int p = 0; p < NP; p++) {
        float e = E[p * HW + j];               // coalesced
        a0 += S[p * HW + i0 + 0] * e;          // wave-uniform -> scalar
        a1 += S[p * HW + i0 + 1] * e;
        a2 += S[p * HW + i0 + 2] * e;
        a3 += S[p * HW + i0 + 3] * e;
    }
    out[(i0 + 0) * HW + j] = a0;
    out[(i0 + 1) * HW + j] = a1;
    out[(i0 + 2) * HW + j] = a2;
    out[(i0 + 3) * HW + j] = a3;
}

// ---------------- launcher ----------------

extern "C" void kernel_launch(void* const* d_in, const int* in_sizes, int n_in,
                              void* d_out, int out_size, void* d_ws, size_t ws_size,
                              hipStream_t stream) {
    const float* X = (const float*)d_in[0];
    const float* Y = (const float*)d_in[1];
    float* out = (float*)d_out;

    float* ws = (float*)d_ws;
    float* x1 = ws;                       // 512*512
    float* S  = x1 + HW * HW;             // 128*512
    float* ST = S + NP * HW;              // 512*128
    float* L  = ST + HW * NP;             // 128*128
    float* E  = L + NP * NP;              // 128*512
    float* P  = E + NP * HW;              // 8*128*512 (m1 partials)

    k_prep<<<dim3(1344),        dim3(256), 0, stream>>>(X, Y, x1, S, ST, L);
    k_m1  <<<dim3(2, 16, 8),    dim3(256), 0, stream>>>(S, x1, P);
    k_m23 <<<dim3(NP),          dim3(512), 0, stream>>>(P, ST, L, S, E);
    k_m4  <<<dim3(2, 128),      dim3(256), 0, stream>>>(S, E, out);
}

// Round 3
// 77.866 us; speedup vs baseline: 1.1270x; 1.0355x over previous
//
#include <hip/hip_runtime.h>
#include <math.h>

// JacobiMachine: 1000 steps of masked 5-point Jacobi averaging on 512x512.
// Spectral method (exact): step 1 explicit, steps 2..1000 via eigen-basis
//   phi_m[i]=sin(m*pi*i/511), lam_mn=0.5*(cos(m*pi/511)+cos(n*pi/511)).
//
// Round 10:
//  (a) NP 128 -> 96 (48 modes/corner): largest discarded |lam|^999 = 1.3e-10
//      (pair (49,1)), seven orders below observed absmax 4.88e-4. Cuts
//      m1/m23/m4 inner work + L2 traffic x0.75.
//  (b) ST produced by transposed stores in the S branch (same fp64 sin value,
//      4 stores) -- halves the fp64 sin count; drops the ST branch.
//  (c) keeps R9 structure: no atomics (P partials), fused m23 (512 thr),
//      binary-exp for lam^999, sin mirror S[95-pa][i]=(-1)^(i+1)S[pa][i].
// Harness floor ~70us (256MB re-poison fills at ~41us each in rocprof);
// controllable share is kernels + node gaps.

#define HW 512
#define NP 96
#define NC 48   // modes per corner

__device__ __forceinline__ int mode_of(int p) {   // p=0..95 -> {1..48} u {463..510}
    return (p < NC) ? (p + 1) : (p + 415);
}

__device__ __forceinline__ float gauss(const float* __restrict__ X,
                                       const float* __restrict__ Y, int idx) {
    float dx = X[idx] - 0.5f, dy = Y[idx] - 0.5f;
    return expf(-50.0f * (dx * dx + dy * dy));
}

// Block ranges:
//  [0,1024)    x1[idx] = masked 5-pt avg of gaussian (== one reference step)
//  [1024,1120) S[pa][i] + mirror S[95-pa][i] + ST[i][pa] + ST[i][95-pa]
//              (pa in [0,48), one fp64 sin per entry, 4 stores)
//  [1120,1156) L[p][q] = lam_pq^999*(2/511)^2  (binary exponentiation)
__global__ void k_prep(const float* __restrict__ X, const float* __restrict__ Y,
                       float* __restrict__ x1, float* __restrict__ S,
                       float* __restrict__ ST, float* __restrict__ L) {
    int b = blockIdx.x, t = threadIdx.x;
    if (b < 1024) {
        int idx = b * 256 + t;
        int i = idx >> 9, j = idx & 511;
        float v = 0.0f;
        if (i > 0 && i < HW - 1 && j > 0 && j < HW - 1) {
            v = 0.25f * (gauss(X, Y, idx - HW) + gauss(X, Y, idx + HW) +
                         gauss(X, Y, idx - 1)  + gauss(X, Y, idx + 1));
        }
        x1[idx] = v;
    } else if (b < 1120) {
        int idx = (b - 1024) * 256 + t;              // 48 rows x 512 = 24576
        int pa = idx >> 9, i = idx & 511;            // pa in [0,48), m = pa+1
        long tt = ((long)(pa + 1) * (long)i) % 1022; // exact reduction
        float s = (float)sin((double)tt * (M_PI / 511.0));
        float sm = (i & 1) ? s : -s;                 // m' = 511-m mirror
        S[pa * HW + i] = s;
        S[(95 - pa) * HW + i] = sm;
        ST[i * NP + pa] = s;
        ST[i * NP + (95 - pa)] = sm;
    } else {
        int idx = (b - 1120) * 256 + t;              // 96*96 = 9216
        if (idx >= NP * NP) return;
        int p = idx / NP, q = idx % NP;
        double lp = cos((double)mode_of(p) * M_PI / 511.0);
        double lq = cos((double)mode_of(q) * M_PI / 511.0);
        double lam = 0.5 * (lp + lq);
        // |lam|^999 via square-and-multiply (999 = 0b1111100111)
        double r = 1.0, base = fabs(lam);
        int e = 999;
        #pragma unroll
        for (int k = 0; k < 10; k++) {
            if (e & 1) r *= base;
            base *= base;
            e >>= 1;
        }
        if (lam < 0.0) r = -r;                       // 999 odd
        L[idx] = (float)(r * (2.0 / 511.0) * (2.0 / 511.0));
    }
}

// P[iz][p][j] = sum_{i in chunk iz} S[p,i]*x1[i,j]   (plain stores, no atomics)
// grid (jc=2, pg=12, ic=8) x 256 = 192 blocks, 8 p-rows/block:
// x1 L2 traffic 12MB, 8-chain ILP, wave-uniform S rows -> scalar loads.
__global__ void k_m1(const float* __restrict__ S, const float* __restrict__ x1,
                     float* __restrict__ P) {
    int j = blockIdx.x * 256 + threadIdx.x;
    int p0 = blockIdx.y * 8;
    int iz = blockIdx.z;
    int i0 = iz * 64;
    const float* Sb = S + p0 * HW + i0;        // wave-uniform -> scalar loads
    const float* xp = x1 + i0 * HW + j;        // coalesced, L2-resident
    float a[8] = {0.f, 0.f, 0.f, 0.f, 0.f, 0.f, 0.f, 0.f};
    #pragma unroll 8
    for (int i = 0; i < 64; i++) {
        float x = xp[i * HW];
        #pragma unroll
        for (int k = 0; k < 8; k++) a[k] += Sb[k * HW + i] * x;
    }
    float* Pp = P + iz * NP * HW + p0 * HW + j;
    #pragma unroll
    for (int k = 0; k < 8; k++) Pp[k * HW] = a[k];
}

// Fused m2+m3, one block per p (96 blocks x 512 threads = 8 waves):
//  load:    c1[j]   = sum_{iz=0..7} P[iz][p][j]            (8 coalesced loads)
//  phase 1: part[jg*128+q] = sum_{j in quarter jg} c1[j]*ST[j,q]  (q<96 active)
//           drow[q] = (sum of 4 parts) * L[p,q]
//  phase 2: E[p][t] = sum_q drow[q]*S[q,t]                 (1 j-column/thread)
__global__ void k_m23(const float* __restrict__ P, const float* __restrict__ ST,
                      const float* __restrict__ L, const float* __restrict__ S,
                      float* __restrict__ E) {
    __shared__ float c1[HW];
    __shared__ float part[512];
    __shared__ float drow[NP];
    int p = blockIdx.x, t = threadIdx.x;
    // sum the 8 m1 partials for row p
    {
        const float* Pp = P + p * HW + t;
        float s0 = 0.f, s1 = 0.f;
        #pragma unroll
        for (int iz = 0; iz < 8; iz += 2) {
            s0 += Pp[iz * NP * HW];
            s1 += Pp[(iz + 1) * NP * HW];
        }
        c1[t] = s0 + s1;
    }
    __syncthreads();
    // phase 1: quarter-j reduction; q = t&127 active when q < 96
    int q = t & 127, jg = t >> 7;
    if (q < NP) {
        const float* STp = ST + (jg * 128) * NP + q;
        const float* cc = c1 + jg * 128;
        float b0 = 0.f, b1 = 0.f;
        #pragma unroll 8
        for (int j = 0; j < 128; j += 2) {
            b0 += cc[j] * STp[j * NP];
            b1 += cc[j + 1] * STp[(j + 1) * NP];
        }
        part[t] = b0 + b1;
    }
    __syncthreads();
    if (t < NP)
        drow[t] = (part[t] + part[t + 128] + part[t + 256] + part[t + 384]) * L[p * NP + t];
    __syncthreads();
    // phase 2: one output column per thread (S reads coalesced, drow broadcast)
    float e0 = 0.f, e1 = 0.f;
    #pragma unroll 8
    for (int qq = 0; qq < NP; qq += 2) {
        e0 += drow[qq] * S[qq * HW + t];
        e1 += drow[qq + 1] * S[(qq + 1) * HW + t];
    }
    E[p * HW + t] = e0 + e1;
}

// out[i][j] = sum_p S[p,i]*E[p,j]
// grid (jc=2, ig=128) x 256 = 256 blocks, 4 i-rows/block (25MB E L2 traffic).
// Boundary exact 0 via S[p][0]=S[p][511]=0.
__global__ void k_m4(const float* __restrict__ S, const float* __restrict__ E,
                     float* __restrict__ out) {
    int j = blockIdx.x * 256 + threadIdx.x;
    int i0 = blockIdx.y * 4;
    float a0 = 0.f, a1 = 0.f, a2 = 0.f, a3 = 0.f;
    #pragma unroll 16
    for (int p = 0; p < NP; p++) {
        float e = E[p * HW + j];               // coalesced
        a0 += S[p * HW + i0 + 0] * e;          // wave-uniform -> scalar
        a1 += S[p * HW + i0 + 1] * e;
        a2 += S[p * HW + i0 + 2] * e;
        a3 += S[p * HW + i0 + 3] * e;
    }
    out[(i0 + 0) * HW + j] = a0;
    out[(i0 + 1) * HW + j] = a1;
    out[(i0 + 2) * HW + j] = a2;
    out[(i0 + 3) * HW + j] = a3;
}

// ---------------- launcher ----------------

extern "C" void kernel_launch(void* const* d_in, const int* in_sizes, int n_in,
                              void* d_out, int out_size, void* d_ws, size_t ws_size,
                              hipStream_t stream) {
    const float* X = (const float*)d_in[0];
    const float* Y = (const float*)d_in[1];
    float* out = (float*)d_out;

    float* ws = (float*)d_ws;
    float* x1 = ws;                       // 512*512
    float* S  = x1 + HW * HW;             // 96*512
    float* ST = S + NP * HW;              // 512*96
    float* L  = ST + HW * NP;             // 96*96
    float* E  = L + NP * NP;              // 96*512
    float* P  = E + NP * HW;              // 8*96*512 (m1 partials)

    k_prep<<<dim3(1156),        dim3(256), 0, stream>>>(X, Y, x1, S, ST, L);
    k_m1  <<<dim3(2, 12, 8),    dim3(256), 0, stream>>>(S, x1, P);
    k_m23 <<<dim3(NP),          dim3(512), 0, stream>>>(P, ST, L, S, E);
    k_m4  <<<dim3(2, 128),      dim3(256), 0, stream>>>(S, E, out);
}

// Round 5
// 72.428 us; speedup vs baseline: 1.2116x; 1.0751x over previous
//
#include <hip/hip_runtime.h>
#include <math.h>

// JacobiMachine: 1000 steps of masked 5-point Jacobi averaging on 512x512.
// Spectral method (exact): step 1 explicit, steps 2..1000 via eigen-basis
//   phi_m[i]=sin(m*pi*i/511), lam_mn=0.5*(cos(m*pi/511)+cos(n*pi/511)).
//
// Round 12: identical to Round 11 (resubmit). R11 aborted on a fresh
// container (preloaded=0, faulthandler dump of pytest main loop, no HIP
// fault message); full index audit found no OOB (max P index 524287 ==
// extent-1, all ST/S/E reads in bounds). Treating as infra flake;
// resubmitting unchanged to isolate. Design:
//  (a) NP 64 (32 modes/corner): largest discarded |lam|^999 = 3.3e-5
//      (pair (33,1)), coefficient-weighted output error < 2e-6 (~300x
//      below observed absmax 4.88e-4).
//  (b) m1: 16 iz-chunks of 32 i-rows, 8 p-rows/block, plain stores.
//  (c) L[p][q] inline in m23's drow scaling (2 cos + 17 fp64 mul/block).
// Harness floor ~70us (256MB re-poison fills at ~41us each in rocprof).

#define HW 512
#define NP 64
#define NC 32   // modes per corner

__device__ __forceinline__ int mode_of(int p) {   // p=0..63 -> {1..32} u {479..510}
    return (p < NC) ? (p + 1) : (p + 447);
}

__device__ __forceinline__ float gauss(const float* __restrict__ X,
                                       const float* __restrict__ Y, int idx) {
    float dx = X[idx] - 0.5f, dy = Y[idx] - 0.5f;
    return expf(-50.0f * (dx * dx + dy * dy));
}

// Block ranges:
//  [0,1024)    x1[idx] = masked 5-pt avg of gaussian (== one reference step)
//  [1024,1088) S[pa][i] + mirror S[63-pa][i] + ST[i][pa] + ST[i][63-pa]
//              (pa in [0,32), one fp64 sin per entry, 4 stores;
//               mirror: sin((511-m)pi i/511) = (-1)^(i+1) sin(m pi i/511))
__global__ void k_prep(const float* __restrict__ X, const float* __restrict__ Y,
                       float* __restrict__ x1, float* __restrict__ S,
                       float* __restrict__ ST) {
    int b = blockIdx.x, t = threadIdx.x;
    if (b < 1024) {
        int idx = b * 256 + t;
        int i = idx >> 9, j = idx & 511;
        float v = 0.0f;
        if (i > 0 && i < HW - 1 && j > 0 && j < HW - 1) {
            v = 0.25f * (gauss(X, Y, idx - HW) + gauss(X, Y, idx + HW) +
                         gauss(X, Y, idx - 1)  + gauss(X, Y, idx + 1));
        }
        x1[idx] = v;
    } else {
        int idx = (b - 1024) * 256 + t;              // 32 rows x 512 = 16384
        int pa = idx >> 9, i = idx & 511;            // pa in [0,32), m = pa+1
        long tt = ((long)(pa + 1) * (long)i) % 1022; // exact reduction
        float s = (float)sin((double)tt * (M_PI / 511.0));
        float sm = (i & 1) ? s : -s;                 // m' = 511-m mirror
        S[pa * HW + i] = s;
        S[(63 - pa) * HW + i] = sm;
        ST[i * NP + pa] = s;
        ST[i * NP + (63 - pa)] = sm;
    }
}

// P[iz][p][j] = sum_{i in chunk iz} S[p,i]*x1[i,j]   (plain stores, no atomics)
// grid (jc=2, pg=8, ic=16) x 256 = 256 blocks, 8 p-rows/block, 32-i chunks:
// 8-chain ILP, wave-uniform S rows -> scalar loads, x1 coalesced L2 reads.
__global__ void k_m1(const float* __restrict__ S, const float* __restrict__ x1,
                     float* __restrict__ P) {
    int j = blockIdx.x * 256 + threadIdx.x;
    int p0 = blockIdx.y * 8;
    int iz = blockIdx.z;
    int i0 = iz * 32;
    const float* Sb = S + p0 * HW + i0;        // wave-uniform -> scalar loads
    const float* xp = x1 + i0 * HW + j;        // coalesced, L2-resident
    float a[8] = {0.f, 0.f, 0.f, 0.f, 0.f, 0.f, 0.f, 0.f};
    #pragma unroll 8
    for (int i = 0; i < 32; i++) {
        float x = xp[i * HW];
        #pragma unroll
        for (int k = 0; k < 8; k++) a[k] += Sb[k * HW + i] * x;
    }
    float* Pp = P + iz * NP * HW + p0 * HW + j;
    #pragma unroll
    for (int k = 0; k < 8; k++) Pp[k * HW] = a[k];
}

// Fused m2+m3, one block per p (64 blocks x 512 threads = 8 waves):
//  load:    c1[j]   = sum_{iz=0..15} P[iz][p][j]           (16 coalesced loads)
//  phase 1: part[jg*64+q] = sum_{j in eighth jg} c1[j]*ST[j,q]  (all threads)
//           drow[q] = (sum of 8 parts) * L[p,q],  L computed inline (fp64)
//  phase 2: E[p][t] = sum_q drow[q]*S[q,t]                 (1 j-column/thread)
__global__ void k_m23(const float* __restrict__ P, const float* __restrict__ ST,
                      const float* __restrict__ S, float* __restrict__ E) {
    __shared__ float c1[HW];
    __shared__ float part[512];
    __shared__ float drow[NP];
    int p = blockIdx.x, t = threadIdx.x;
    // sum the 16 m1 partials for row p
    {
        const float* Pp = P + p * HW + t;
        float s0 = 0.f, s1 = 0.f;
        #pragma unroll
        for (int iz = 0; iz < 16; iz += 2) {
            s0 += Pp[iz * NP * HW];
            s1 += Pp[(iz + 1) * NP * HW];
        }
        c1[t] = s0 + s1;
    }
    __syncthreads();
    // phase 1: eighth-j reduction, q = t&63, jg = t>>6 (all 512 threads active)
    int q = t & 63, jg = t >> 6;
    {
        const float* STp = ST + (jg * 64) * NP + q;
        const float* cc = c1 + jg * 64;
        float b0 = 0.f, b1 = 0.f;
        #pragma unroll 8
        for (int j = 0; j < 64; j += 2) {
            b0 += cc[j] * STp[j * NP];
            b1 += cc[j + 1] * STp[(j + 1) * NP];
        }
        part[t] = b0 + b1;
    }
    __syncthreads();
    if (t < NP) {
        float ps = 0.f;
        #pragma unroll
        for (int g = 0; g < 8; g++) ps += part[t + 64 * g];
        // L[p][t] inline: lam^999 * (2/511)^2, binary exponentiation
        double lp = cos((double)mode_of(p) * M_PI / 511.0);
        double lq = cos((double)mode_of(t) * M_PI / 511.0);
        double lam = 0.5 * (lp + lq);
        double r = 1.0, base = fabs(lam);
        int e = 999;                                 // 999 = 0b1111100111
        #pragma unroll
        for (int k = 0; k < 10; k++) {
            if (e & 1) r *= base;
            base *= base;
            e >>= 1;
        }
        if (lam < 0.0) r = -r;                       // 999 odd
        drow[t] = ps * (float)(r * (2.0 / 511.0) * (2.0 / 511.0));
    }
    __syncthreads();
    // phase 2: one output column per thread (S reads coalesced, drow broadcast)
    float e0 = 0.f, e1 = 0.f;
    #pragma unroll 8
    for (int qq = 0; qq < NP; qq += 2) {
        e0 += drow[qq] * S[qq * HW + t];
        e1 += drow[qq + 1] * S[(qq + 1) * HW + t];
    }
    E[p * HW + t] = e0 + e1;
}

// out[i][j] = sum_p S[p,i]*E[p,j]
// grid (jc=2, ig=128) x 256 = 256 blocks, 4 i-rows/block.
// Boundary exact 0 via S[p][0]=S[p][511]=0.
__global__ void k_m4(const float* __restrict__ S, const float* __restrict__ E,
                     float* __restrict__ out) {
    int j = blockIdx.x * 256 + threadIdx.x;
    int i0 = blockIdx.y * 4;
    float a0 = 0.f, a1 = 0.f, a2 = 0.f, a3 = 0.f;
    #pragma unroll 16
    for (int p = 0; p < NP; p++) {
        float e = E[p * HW + j];               // coalesced
        a0 += S[p * HW + i0 + 0] * e;          // wave-uniform -> scalar
        a1 += S[p * HW + i0 + 1] * e;
        a2 += S[p * HW + i0 + 2] * e;
        a3 += S[p * HW + i0 + 3] * e;
    }
    out[(i0 + 0) * HW + j] = a0;
    out[(i0 + 1) * HW + j] = a1;
    out[(i0 + 2) * HW + j] = a2;
    out[(i0 + 3) * HW + j] = a3;
}

// ---------------- launcher ----------------

extern "C" void kernel_launch(void* const* d_in, const int* in_sizes, int n_in,
                              void* d_out, int out_size, void* d_ws, size_t ws_size,
                              hipStream_t stream) {
    const float* X = (const float*)d_in[0];
    const float* Y = (const float*)d_in[1];
    float* out = (float*)d_out;

    float* ws = (float*)d_ws;
    float* x1 = ws;                       // 512*512
    float* S  = x1 + HW * HW;             // 64*512
    float* ST = S + NP * HW;              // 512*64
    float* E  = ST + HW * NP;             // 64*512
    float* P  = E + NP * HW;              // 16*64*512 (m1 partials)

    k_prep<<<dim3(1088),        dim3(256), 0, stream>>>(X, Y, x1, S, ST);
    k_m1  <<<dim3(2, 8, 16),    dim3(256), 0, stream>>>(S, x1, P);
    k_m23 <<<dim3(NP),          dim3(512), 0, stream>>>(P, ST, S, E);
    k_m4  <<<dim3(2, 128),      dim3(256), 0, stream>>>(S, E, out);
}

// Round 6
// 70.519 us; speedup vs baseline: 1.2444x; 1.0271x over previous
//
#include <hip/hip_runtime.h>
#include <math.h>

// JacobiMachine: 1000 steps of masked 5-point Jacobi averaging on 512x512.
// Spectral method (exact): step 1 explicit, steps 2..1000 via eigen-basis
//   phi_m[i]=sin(m*pi*i/511), lam_mn=0.5*(cos(m*pi/511)+cos(n*pi/511)).
//
// Round 13: mirror-parity halving. sin((511-m)pi k/511) = (-1)^(k+1) sin(m pi k/511)
// lets every transform produce mirror-row pairs from one set of multiplies by
// splitting accumulation on index parity:
//  - m1: even/odd-i sums -> C1[pa]=ae+ao, C1[63-pa]=ao-ae (FMA, S reads /2)
//  - m23 ph1: even/odd-j sums -> part[qa]=se+so, part[63-qa]=so-se
//  - m23 ph2: e = sum_qa S[qa,t] * (t odd ? drow[qa]+drow[63-qa] : drow[qa]-drow[63-qa])
//  - m4: ep/em = E[pa]+-E[63-pa]; even rows use em, odd rows ep
// S rows >=32 / ST cols >=32 become dead -> tables halve, prep mirror stores drop.
// NP=64 (32 modes/corner) unchanged: discarded |lam|^999 <= 3.3e-5, error < 2e-6.
// Harness floor ~70us-ish (256MB re-poison fills at ~41us each in rocprof).

#define HW 512
#define NP 64
#define NC 32   // modes per corner; only pa<NC tables are stored

__device__ __forceinline__ int mode_of(int p) {   // p=0..63 -> {1..32} u {479..510}
    return (p < NC) ? (p + 1) : (p + 447);
}

__device__ __forceinline__ float gauss(const float* __restrict__ X,
                                       const float* __restrict__ Y, int idx) {
    float dx = X[idx] - 0.5f, dy = Y[idx] - 0.5f;
    return expf(-50.0f * (dx * dx + dy * dy));
}

// Block ranges:
//  [0,1024)    x1[idx] = masked 5-pt avg of gaussian (== one reference step)
//  [1024,1088) S[pa][i] (32 x 512) and ST[i][pa] (512 x 32), pa<32 only
__global__ void k_prep(const float* __restrict__ X, const float* __restrict__ Y,
                       float* __restrict__ x1, float* __restrict__ S,
                       float* __restrict__ ST) {
    int b = blockIdx.x, t = threadIdx.x;
    if (b < 1024) {
        int idx = b * 256 + t;
        int i = idx >> 9, j = idx & 511;
        float v = 0.0f;
        if (i > 0 && i < HW - 1 && j > 0 && j < HW - 1) {
            v = 0.25f * (gauss(X, Y, idx - HW) + gauss(X, Y, idx + HW) +
                         gauss(X, Y, idx - 1)  + gauss(X, Y, idx + 1));
        }
        x1[idx] = v;
    } else {
        int idx = (b - 1024) * 256 + t;              // 32 rows x 512 = 16384
        int pa = idx >> 9, i = idx & 511;            // pa in [0,32), m = pa+1
        long tt = ((long)(pa + 1) * (long)i) % 1022; // exact reduction
        float s = (float)sin((double)tt * (M_PI / 511.0));
        S[pa * HW + i] = s;
        ST[i * NC + pa] = s;
    }
}

// P[iz][row][j] partial of C1[row][j] = sum_i S-basis * x1[i,j]; parity trick:
// rows pa0..pa0+7 AND mirrors 63-pa from the same multiplies.
// grid (jc=2, pg=4, ic=32) x 256 = 256 blocks, 16-i chunks:
// per thread 16 x1 loads, 128 FMA, 16 stores; S reads wave-uniform scalars.
__global__ void k_m1(const float* __restrict__ S, const float* __restrict__ x1,
                     float* __restrict__ P) {
    int j = blockIdx.x * 256 + threadIdx.x;
    int pa0 = blockIdx.y * 8;                  // 0,8,16,24
    int iz = blockIdx.z;                       // 0..31
    int i0 = iz * 16;                          // even
    const float* Sb = S + pa0 * HW + i0;       // wave-uniform -> scalar loads
    const float* xp = x1 + i0 * HW + j;        // coalesced, L2-resident
    float ae[8] = {0.f, 0.f, 0.f, 0.f, 0.f, 0.f, 0.f, 0.f};
    float ao[8] = {0.f, 0.f, 0.f, 0.f, 0.f, 0.f, 0.f, 0.f};
    #pragma unroll
    for (int i = 0; i < 16; i++) {
        float x = xp[i * HW];
        if ((i & 1) == 0) {
            #pragma unroll
            for (int k = 0; k < 8; k++) ae[k] += Sb[k * HW + i] * x;
        } else {
            #pragma unroll
            for (int k = 0; k < 8; k++) ao[k] += Sb[k * HW + i] * x;
        }
    }
    float* Pp = P + iz * NP * HW + j;
    #pragma unroll
    for (int k = 0; k < 8; k++) {
        Pp[(pa0 + k) * HW]      = ae[k] + ao[k];   // row pa
        Pp[(63 - pa0 - k) * HW] = ao[k] - ae[k];   // mirror row 63-pa
    }
}

// Fused m2+m3, one block per p (64 blocks x 512 threads = 8 waves):
//  load:  c1[j] = sum_{iz<32} P[iz][p][j]                    (32 coalesced, 4-way ILP)
//  ph1:   qa=t&31, jg=t>>5 (16 j-groups of 32): even/odd-j sums pe/po
//  comb:  t<32: dlo=(se+so)*L[p][qa], dhi=(so-se)*L[p][63-qa] (L inline, fp64)
//         dp[qa]=dlo+dhi (odd cols), dm[qa]=dlo-dhi (even cols)
//  ph2:   E[p][t] = sum_{qa<32} sel[qa]*S[qa,t], sel = (t&1)? dp : dm
__global__ void k_m23(const float* __restrict__ P, const float* __restrict__ ST,
                      const float* __restrict__ S, float* __restrict__ E) {
    __shared__ float c1[HW];
    __shared__ float pe[512], po[512];
    __shared__ float dp[NC], dm[NC];
    int p = blockIdx.x, t = threadIdx.x;
    // sum the 32 m1 partials for row p
    {
        const float* Pp = P + p * HW + t;
        float s0 = 0.f, s1 = 0.f, s2 = 0.f, s3 = 0.f;
        #pragma unroll
        for (int iz = 0; iz < 32; iz += 4) {
            s0 += Pp[(iz + 0) * NP * HW];
            s1 += Pp[(iz + 1) * NP * HW];
            s2 += Pp[(iz + 2) * NP * HW];
            s3 += Pp[(iz + 3) * NP * HW];
        }
        c1[t] = (s0 + s1) + (s2 + s3);
    }
    __syncthreads();
    // phase 1: 16 j-groups of 32; LDS c1 reads are 2-address broadcasts
    int qa = t & 31, jg = t >> 5;
    {
        const float* STp = ST + (jg * 32) * NC + qa;   // 128B coalesced per half-wave
        const float* cc = c1 + jg * 32;
        float be = 0.f, bo = 0.f;
        #pragma unroll
        for (int jj = 0; jj < 32; jj += 2) {
            be += cc[jj] * STp[jj * NC];
            bo += cc[jj + 1] * STp[(jj + 1) * NC];
        }
        pe[t] = be;
        po[t] = bo;
    }
    __syncthreads();
    if (t < NC) {
        float se = 0.f, so = 0.f;
        #pragma unroll
        for (int g = 0; g < 16; g++) {
            se += pe[g * 32 + t];
            so += po[g * 32 + t];
        }
        float dlo = se + so;                   // D row-term for q = t
        float dhi = so - se;                   // for q = 63 - t
        // L[p][t], L[p][63-t] inline: lam^999*(2/511)^2, binary exponentiation
        double lp = cos((double)mode_of(p) * M_PI / 511.0);
        double ca = cos((double)(t + 1) * M_PI / 511.0);   // mode_of(t)=t+1 (t<32)
        double lam1 = 0.5 * (lp + ca);                     // q = t
        double lam2 = 0.5 * (lp - ca);                     // q = 63-t (mode 510-t)
        double r1 = 1.0, b1 = fabs(lam1);
        double r2 = 1.0, b2 = fabs(lam2);
        int e = 999;                                       // 0b1111100111
        #pragma unroll
        for (int k = 0; k < 10; k++) {
            if (e & 1) { r1 *= b1; r2 *= b2; }
            b1 *= b1; b2 *= b2;
            e >>= 1;
        }
        if (lam1 < 0.0) r1 = -r1;                          // 999 odd
        if (lam2 < 0.0) r2 = -r2;
        const double sc = (2.0 / 511.0) * (2.0 / 511.0);
        dlo *= (float)(r1 * sc);
        dhi *= (float)(r2 * sc);
        dp[t] = dlo + dhi;                                 // for odd columns
        dm[t] = dlo - dhi;                                 // for even columns
    }
    __syncthreads();
    // phase 2: 32 iterations; S rows <32 only, coalesced; sel reads broadcast
    const float* sel = (t & 1) ? dp : dm;
    float e0 = 0.f, e1 = 0.f;
    #pragma unroll
    for (int q2 = 0; q2 < NC; q2 += 2) {
        e0 += sel[q2] * S[q2 * HW + t];
        e1 += sel[q2 + 1] * S[(q2 + 1) * HW + t];
    }
    E[p * HW + t] = e0 + e1;
}

// out[i][j] = sum_p S[p,i]*E[p,j]; parity trick over mirror pairs (pa, 63-pa):
// ep/em = E[pa]+-E[63-pa]; even rows i use em, odd rows ep.
// grid (jc=2, ig=128) x 256 = 256 blocks, 4 i-rows/block (i0 even).
// Boundary exact 0 via S[pa][0]=S[pa][511]=0.
__global__ void k_m4(const float* __restrict__ S, const float* __restrict__ E,
                     float* __restrict__ out) {
    int j = blockIdx.x * 256 + threadIdx.x;
    int i0 = blockIdx.y * 4;
    float a0 = 0.f, a1 = 0.f, a2 = 0.f, a3 = 0.f;
    #pragma unroll 8
    for (int pa = 0; pa < NC; pa++) {
        float elo = E[pa * HW + j];            // coalesced
        float ehi = E[(63 - pa) * HW + j];     // coalesced
        float ep = elo + ehi, em = elo - ehi;
        const float* Sp = S + pa * HW + i0;    // wave-uniform -> scalar
        a0 += Sp[0] * em;                      // i0   even
        a1 += Sp[1] * ep;                      // i0+1 odd
        a2 += Sp[2] * em;                      // i0+2 even
        a3 += Sp[3] * ep;                      // i0+3 odd
    }
    out[(i0 + 0) * HW + j] = a0;
    out[(i0 + 1) * HW + j] = a1;
    out[(i0 + 2) * HW + j] = a2;
    out[(i0 + 3) * HW + j] = a3;
}

// ---------------- launcher ----------------

extern "C" void kernel_launch(void* const* d_in, const int* in_sizes, int n_in,
                              void* d_out, int out_size, void* d_ws, size_t ws_size,
                              hipStream_t stream) {
    const float* X = (const float*)d_in[0];
    const float* Y = (const float*)d_in[1];
    float* out = (float*)d_out;

    float* ws = (float*)d_ws;
    float* x1 = ws;                       // 512*512
    float* S  = x1 + HW * HW;             // 32*512
    float* ST = S + NC * HW;              // 512*32
    float* E  = ST + HW * NC;             // 64*512
    float* P  = E + NP * HW;              // 32*64*512 (m1 partials)

    k_prep<<<dim3(1088),        dim3(256), 0, stream>>>(X, Y, x1, S, ST);
    k_m1  <<<dim3(2, 4, 32),    dim3(256), 0, stream>>>(S, x1, P);
    k_m23 <<<dim3(NP),          dim3(512), 0, stream>>>(P, ST, S, E);
    k_m4  <<<dim3(2, 128),      dim3(256), 0, stream>>>(S, E, out);
}